// Round 7
// baseline (128.804 us; speedup 1.0000x reference)
//
#include <hip/hip_runtime.h>

// (B, Lq, Lk, D, C, KW) = (8, 1024, 1024, 512, 512, 3)
//
// Algebra:
//   out[b,i,j] = q[i]·(V[b,j] + W_bias) + t[b,j] + b_bias + bias_b
//   V[b,j,d]   = sum_{c,w} W[d, c*3+w] * kpad[b, j+w, c]     (K=1536 GEMM, bf16)
//   t[b,j]     = s_0[b,j-1] + s_1[b,j] + s_2[b,j+1],  s_w[b,j] = dot(k[b,j], bk_w)
// s_w computed inside the k->bf16 conversion pass; t reconstructed in gemm_QV.
// Wt2 is 512 x 1536 bf16 (W permuted to [d][w*512+c]).  V is 8192 x 512 bf16.
//
// This round: gemm_V gets a 3-deep LDS pipeline with COUNTED vmcnt(6) at raw
// s_barriers (T3/T4 minimum): loads issued 2 K-steps ahead stay in flight
// across barriers instead of draining to 0 every step. gemm_QV/cvt unchanged.

typedef __attribute__((ext_vector_type(8))) short s8vec;    // 8 x bf16 (4 VGPRs)
typedef __attribute__((ext_vector_type(4))) float floatx4;  // MFMA accumulator

__device__ __forceinline__ unsigned short f2bf(float f) {
    union { float f; unsigned u; } v; v.f = f;
    unsigned r = (v.u + 0x7FFFu + ((v.u >> 16) & 1u)) >> 16;
    return (unsigned short)r;
}

__device__ __forceinline__ void gl2lds16(const void* g, void* l) {
    __builtin_amdgcn_global_load_lds(
        (__attribute__((address_space(1))) void*)(g),
        (__attribute__((address_space(3))) void*)(l), 16, 0, 0);
}

#define MEMFENCE() asm volatile("" ::: "memory")

// ---- fused conversions: q->bf16 | k->padded bf16 + s_w partial dots |
//      W -> Wt2[d][w*512+c] bf16 | kp zero-pad rows | s halo zeros ----
__global__ void cvt_all(const float* __restrict__ q, const float* __restrict__ k,
                        unsigned short* __restrict__ qbf, unsigned short* __restrict__ kp,
                        const float* __restrict__ W, unsigned short* __restrict__ Wt2,
                        const float* __restrict__ b_kernel, float* __restrict__ spart) {
    __shared__ float ldsw[1536];
    int blk = blockIdx.x;
    if (blk < 2048) {                           // q: 8*1024*512 f32 -> bf16, 8/thread
        int t = blk * 256 + threadIdx.x;        // 0..524287
        const float4* p = (const float4*)q + 2 * (size_t)t;
        float4 a = p[0], b = p[1];
        union { unsigned short s[8]; uint4 v; } o;
        o.s[0]=f2bf(a.x); o.s[1]=f2bf(a.y); o.s[2]=f2bf(a.z); o.s[3]=f2bf(a.w);
        o.s[4]=f2bf(b.x); o.s[5]=f2bf(b.y); o.s[6]=f2bf(b.z); o.s[7]=f2bf(b.w);
        ((uint4*)qbf)[t] = o.v;
    } else if (blk < 3072) {                    // k: row-per-wave convert + s_w dots
        int p = blk - 2048;                     // 0..1023
        int b = p >> 7;                         // 0..7
        // stage b_kernel permuted [w][c] in f32
        for (int e = threadIdx.x; e < 1536; e += 256) {
            float v = b_kernel[e];
            int c = e / 3, w = e - c * 3;
            ldsw[w * 512 + c] = v;
        }
        __syncthreads();
        int wave = threadIdx.x >> 6, lane = threadIdx.x & 63;
        float bw[3][8];
        #pragma unroll
        for (int w = 0; w < 3; w++)
            #pragma unroll
            for (int i = 0; i < 8; i++) bw[w][i] = ldsw[w * 512 + lane * 8 + i];
        const float* kb = k + (size_t)b * 1024 * 512;
        #pragma unroll
        for (int rr = 0; rr < 2; rr++) {
            int j = (p & 127) * 8 + wave * 2 + rr;
            const float4* kr = (const float4*)(kb + (size_t)j * 512) + lane * 2;
            float4 a0 = kr[0], a1 = kr[1];
            union { unsigned short s[8]; uint4 v; } o;
            o.s[0]=f2bf(a0.x); o.s[1]=f2bf(a0.y); o.s[2]=f2bf(a0.z); o.s[3]=f2bf(a0.w);
            o.s[4]=f2bf(a1.x); o.s[5]=f2bf(a1.y); o.s[6]=f2bf(a1.z); o.s[7]=f2bf(a1.w);
            *(uint4*)(kp + ((size_t)(b * 1028 + j + 1) * 512 + lane * 8)) = o.v;
            float s0 = a0.x*bw[0][0] + a0.y*bw[0][1] + a0.z*bw[0][2] + a0.w*bw[0][3]
                     + a1.x*bw[0][4] + a1.y*bw[0][5] + a1.z*bw[0][6] + a1.w*bw[0][7];
            float s1 = a0.x*bw[1][0] + a0.y*bw[1][1] + a0.z*bw[1][2] + a0.w*bw[1][3]
                     + a1.x*bw[1][4] + a1.y*bw[1][5] + a1.z*bw[1][6] + a1.w*bw[1][7];
            float s2 = a0.x*bw[2][0] + a0.y*bw[2][1] + a0.z*bw[2][2] + a0.w*bw[2][3]
                     + a1.x*bw[2][4] + a1.y*bw[2][5] + a1.z*bw[2][6] + a1.w*bw[2][7];
            #pragma unroll
            for (int off = 32; off > 0; off >>= 1) {
                s0 += __shfl_down(s0, off);
                s1 += __shfl_down(s1, off);
                s2 += __shfl_down(s2, off);
            }
            if (lane == 0) {                    // row j stored at index j+1
                float* sb = spart + b * 1028 + j + 1;
                sb[0]     = s0;
                sb[8224]  = s1;
                sb[16448] = s2;
            }
        }
    } else if (blk < 3584) {                    // Wt2 rows 0..511: one d-row per block
        int d = blk - 3072;
        const float4* wrow = (const float4*)(W + (size_t)d * 1536);
        for (int e = threadIdx.x; e < 384; e += 256) {
            float4 v = wrow[e];
            float va[4] = { v.x, v.y, v.z, v.w };
            #pragma unroll
            for (int i = 0; i < 4; i++) {
                int idx = e * 4 + i;            // idx = c*3 + w
                int c = idx / 3, w = idx - c * 3;
                ldsw[w * 512 + c] = va[i];
            }
        }
        __syncthreads();
        for (int p = threadIdx.x; p < 192; p += 256) {
            union { unsigned short s[8]; uint4 v; } o;
            #pragma unroll
            for (int i = 0; i < 8; i++) o.s[i] = f2bf(ldsw[p * 8 + i]);
            *(uint4*)(Wt2 + (size_t)d * 1536 + p * 8) = o.v;
        }
    } else if (blk < 3592) {                    // kp zero rows 0, 1025..1027
        int z = (blk - 3584) * 256 + threadIdx.x;   // 0..2047
        int b = z >> 8, r = (z >> 6) & 3, ch = z & 63;
        int row = r ? (1024 + r) : 0;
        *(uint4*)(kp + ((size_t)(b * 1028 + row) * 512 + ch * 8)) = make_uint4(0u,0u,0u,0u);
    } else {                                    // s halo zeros (idx 0 and 1025)
        int t = threadIdx.x;
        if (t < 48) {
            int w = t >> 4, rem = t & 15;
            int b = rem >> 1, pos = (rem & 1) ? 1025 : 0;
            spart[w * 8224 + b * 1028 + pos] = 0.0f;
        }
    }
}

// ---- Phase V: V[b*1024+j][n] = bf16( kwin_flat[b,j,:] @ Wt2[n,:]^T + Wb[n] )
//      128m x 64n tiles, 4 waves (2x2), BK=64, grid 512 (8b x 8m x 8n),
//      XCD = batch. LDS rows 128B, XOR-swizzle slot^=(row&7).
//      3-deep pipeline: STAGE(kt+2) each step, raw s_barrier + vmcnt(6)
//      (drain only the older 6 loads; just-issued 6 stay in flight). ----
__global__ __launch_bounds__(256) void gemm_V(const unsigned short* __restrict__ kp,
                                              const unsigned short* __restrict__ Wt2,
                                              const float* __restrict__ Wbias,
                                              unsigned short* __restrict__ V) {
    __shared__ unsigned short lds_a[3][128 * 64];   // 3 x 16 KB
    __shared__ unsigned short lds_b[3][64 * 64];    // 3 x 8 KB   (72 KB total)
    int g = blockIdx.x;                 // 0..511
    int b = g & 7, slot = g >> 3;       // slot 0..63
    int j0 = (slot >> 3) * 128;
    int n0 = (slot & 7) * 64;
    int tid = threadIdx.x, wid = tid >> 6, lane = tid & 63;
    int wm = wid >> 1, wn = wid & 1;
    int crow = lane >> 3;                           // row within 8-row chunk
    int scol = ((lane & 7) ^ crow) * 8;             // inverse-swizzled global col
    const unsigned short* kpb = kp + (size_t)(b * 1028 + j0) * 512;
    floatx4 acc[4][2] = {};

    // exactly 6 wave-uniform loads per wave per STAGE (vmcnt bookkeeping exact)
    auto STAGE = [&](int buf, int kk) {
        #pragma unroll
        for (int s = 0; s < 6; ++s) {
            int t = wid * 6 + s;        // 0..23
            if (t < 16) {               // A: 128 rows x 64k, chunk = 8 rows
                const unsigned short* ga = kpb + (size_t)(t * 8 + crow) * 512 + kk + scol;
                gl2lds16(ga, (char*)lds_a[buf] + t * 1024);
            } else {                    // B: 64 rows x 64k
                int u = t - 16;
                const unsigned short* gb = Wt2 + (size_t)(n0 + u * 8 + crow) * 1536 + kk + scol;
                gl2lds16(gb, (char*)lds_b[buf] + u * 1024);
            }
        }
    };

    STAGE(0, 0);
    STAGE(1, 64);
    asm volatile("s_waitcnt vmcnt(6)" ::: "memory");    // buf0 complete
    __builtin_amdgcn_sched_barrier(0);
    __builtin_amdgcn_s_barrier();
    MEMFENCE();

    int ra = lane & 15, hi = lane >> 4;
    for (int kt = 0; kt < 24; ++kt) {
        int cur = kt % 3;
        if (kt + 2 < 24) STAGE((kt + 2) % 3, (kt + 2) * 64);
        #pragma unroll
        for (int ks = 0; ks < 2; ++ks) {
            s8vec af[4], bfr[2];
            #pragma unroll
            for (int mi = 0; mi < 4; mi++) {
                int R = wm * 64 + mi * 16 + ra;
                af[mi] = *(const s8vec*)((const char*)lds_a[cur] + R * 128 + (((ks << 2) + hi) ^ (R & 7)) * 16);
            }
            #pragma unroll
            for (int ni = 0; ni < 2; ni++) {
                int R = wn * 32 + ni * 16 + ra;
                bfr[ni] = *(const s8vec*)((const char*)lds_b[cur] + R * 128 + (((ks << 2) + hi) ^ (R & 7)) * 16);
            }
            #pragma unroll
            for (int mi = 0; mi < 4; mi++)
                #pragma unroll
                for (int ni = 0; ni < 2; ni++)
                    acc[mi][ni] = __builtin_amdgcn_mfma_f32_16x16x32_bf16(af[mi], bfr[ni], acc[mi][ni], 0, 0, 0);
        }
        if (kt < 23) {
            // before next step's reads of buf[(kt+1)%3]: its 6 loads (issued at
            // kt-1) must land. Outstanding: (kt+1)'s [maybe] + (kt+2)'s 6.
            if (kt < 22) { asm volatile("s_waitcnt vmcnt(6)" ::: "memory"); }
            else         { asm volatile("s_waitcnt vmcnt(0)" ::: "memory"); }
            __builtin_amdgcn_sched_barrier(0);
            __builtin_amdgcn_s_barrier();
            MEMFENCE();
        }
    }

    int cl = lane & 15, qd = lane >> 4;
    #pragma unroll
    for (int mi = 0; mi < 4; mi++) {
        #pragma unroll
        for (int ni = 0; ni < 2; ni++) {
            int col = n0 + wn * 32 + ni * 16 + cl;
            float wb = Wbias[col];
            #pragma unroll
            for (int r = 0; r < 4; r++) {
                int m_g = b * 1024 + j0 + wm * 64 + mi * 16 + qd * 4 + r;
                V[(size_t)m_g * 512 + col] = f2bf(acc[mi][ni][r] + wb);
            }
        }
    }
}

// ---- Phase B': out[b,i,j] = sum_d qbf[b,i,d]*V[b,j,d] + t[b,j] + b_bias + bias_b
//      t[b,j] = s0[j-1] + s1[j] + s2[j+1] via halo-padded spart.
//      128x128 tiles, 4 waves, BK=64 dbuf, grid 512, XCD = batch. ----
__global__ __launch_bounds__(256) void gemm_QV(const unsigned short* __restrict__ qbf,
                                               const unsigned short* __restrict__ V,
                                               const float* __restrict__ spart,
                                               const float* __restrict__ b_bias,
                                               const float* __restrict__ bias_b,
                                               float* __restrict__ out) {
    __shared__ unsigned short lds_a[2][128 * 64];   // 2 x 16 KB
    __shared__ unsigned short lds_b[2][128 * 64];   // 2 x 16 KB
    int g = blockIdx.x;                 // 0..511
    int b = g & 7, slot = g >> 3;       // slot 0..63
    int i0 = (slot >> 3) * 128;
    int j0 = (slot & 7) * 128;
    int tid = threadIdx.x, wid = tid >> 6, lane = tid & 63;
    int wm = wid >> 1, wn = wid & 1;
    int crow = lane >> 3;
    int scol = ((lane & 7) ^ crow) * 8;
    const unsigned short* Ab = qbf + (size_t)b * 1024 * 512;
    const unsigned short* Bb = V + (size_t)b * 1024 * 512;
    floatx4 acc[4][4] = {};

    auto STAGE = [&](int buf, int kk) {
        #pragma unroll
        for (int s = 0; s < 8; ++s) {
            int t = wid * 8 + s;        // 0..31, wave-uniform
            if (t < 16) {
                const unsigned short* ga = Ab + (size_t)(i0 + t * 8 + crow) * 512 + kk + scol;
                gl2lds16(ga, (char*)lds_a[buf] + t * 1024);
            } else {
                int u = t - 16;
                const unsigned short* gb = Bb + (size_t)(j0 + u * 8 + crow) * 512 + kk + scol;
                gl2lds16(gb, (char*)lds_b[buf] + u * 1024);
            }
        }
    };

    STAGE(0, 0);
    __syncthreads();
    int cur = 0;
    int ra = lane & 15, hi = lane >> 4;
    for (int kt = 0; kt < 8; ++kt) {
        if (kt < 7) STAGE(cur ^ 1, (kt + 1) * 64);
        #pragma unroll
        for (int ks = 0; ks < 2; ++ks) {
            s8vec af[4], bfr[4];
            #pragma unroll
            for (int mi = 0; mi < 4; mi++) {
                int R = wm * 64 + mi * 16 + ra;
                af[mi] = *(const s8vec*)((const char*)lds_a[cur] + R * 128 + (((ks << 2) + hi) ^ (R & 7)) * 16);
            }
            #pragma unroll
            for (int ni = 0; ni < 4; ni++) {
                int R = wn * 64 + ni * 16 + ra;
                bfr[ni] = *(const s8vec*)((const char*)lds_b[cur] + R * 128 + (((ks << 2) + hi) ^ (R & 7)) * 16);
            }
            #pragma unroll
            for (int mi = 0; mi < 4; mi++)
                #pragma unroll
                for (int ni = 0; ni < 4; ni++)
                    acc[mi][ni] = __builtin_amdgcn_mfma_f32_16x16x32_bf16(af[mi], bfr[ni], acc[mi][ni], 0, 0, 0);
        }
        if (kt < 7) { __syncthreads(); cur ^= 1; }
    }

    int cl = lane & 15, qd = lane >> 4;
    float bbsum = b_bias[0] + bias_b[0];
    const float* sb = spart + b * 1028;     // [w] stride 8224, row j at idx j+1
    float tv[4];
    #pragma unroll
    for (int ni = 0; ni < 4; ni++) {
        int jg = j0 + wn * 64 + ni * 16 + cl;
        // t[jg] = s0[jg-1] + s1[jg] + s2[jg+1]  (halo zeros at idx 0 / 1025)
        tv[ni] = sb[jg] + sb[8224 + jg + 1] + sb[16448 + jg + 2] + bbsum;
    }
    #pragma unroll
    for (int mi = 0; mi < 4; mi++) {
        #pragma unroll
        for (int r = 0; r < 4; r++) {
            int i_g = i0 + wm * 64 + mi * 16 + qd * 4 + r;
            float* orow = out + ((size_t)(b * 1024 + i_g)) * 1024 + j0;
            #pragma unroll
            for (int ni = 0; ni < 4; ni++) {
                int j_loc = wn * 64 + ni * 16 + cl;
                orow[j_loc] = acc[mi][ni][r] + tv[ni];
            }
        }
    }
}

extern "C" void kernel_launch(void* const* d_in, const int* in_sizes, int n_in,
                              void* d_out, int out_size, void* d_ws, size_t ws_size,
                              hipStream_t stream) {
    const float* q        = (const float*)d_in[0];  // (8,1024,512)
    const float* k        = (const float*)d_in[1];  // (8,1024,512)
    const float* W_kernel = (const float*)d_in[2];  // (512,1536)
    const float* b_kernel = (const float*)d_in[3];  // (1536,)
    const float* W_bias   = (const float*)d_in[4];  // (512,1)
    const float* b_bias   = (const float*)d_in[5];  // (1,)
    const float* bias_b   = (const float*)d_in[6];  // (1,)
    float* out = (float*)d_out;                     // (8,1024,1024)

    // workspace carve (bytes):
    //   q_bf 8M | kp 8.03M + 16K headroom | Wt2 1.5M | V 8M | spart 3*8224*4
    char* ws = (char*)d_ws;
    unsigned short* q_bf = (unsigned short*)(ws);
    unsigned short* kp   = (unsigned short*)(ws + 8388608);
    unsigned short* Wt2  = (unsigned short*)(ws + 8388608 + 8421376 + 16384);
    unsigned short* V    = (unsigned short*)(ws + 8388608 + 8421376 + 16384 + 1572864);
    float*          sp   = (float*)(ws + 8388608 + 8421376 + 16384 + 1572864 + 8388608);

    cvt_all<<<3593, 256, 0, stream>>>(q, k, q_bf, kp, W_kernel, Wt2, b_kernel, sp);
    gemm_V<<<512, 256, 0, stream>>>(kp, Wt2, W_bias, V);
    gemm_QV<<<512, 256, 0, stream>>>(q_bf, V, sp, b_bias, bias_b, out);
}

// Round 8
// 125.803 us; speedup vs baseline: 1.0239x; 1.0239x over previous
//
#include <hip/hip_runtime.h>

// (B, Lq, Lk, D, C, KW) = (8, 1024, 1024, 512, 512, 3)
//
// Algebra:
//   out[b,i,j] = q[i]·(V[b,j] + W_bias) + t[b,j] + b_bias + bias_b
//   V[b,j,d]   = sum_{c,w} W[d, c*3+w] * kpad[b, j+w, c]     (K=1536 GEMM, bf16)
//   t[b,j]     = s_0[b,j-1] + s_1[b,j] + s_2[b,j+1],  s_w[b,j] = dot(k[b,j], bk_w)
//
// Launch structure (this round):
//   1. cvt_kw   : k->kp bf16 + s_w partials, W->Wt2, pads     (~5 us, BW-bound)
//   2. gemm_V+q : blocks 0..511 = V GEMM (R6 2-buffer form, 48 KB LDS ->
//                 3 blocks/CU); blocks 512..2559 = q->bf16 conversion that
//                 co-resides and streams HBM under the MFMA-bound GEMM.
//   3. gemm_QV  : out GEMM (R6 form, unchanged).
// R7 post-mortem: counted-vmcnt deep pipeline NULL in flat 2-barrier loop
// (regime-gated, needs 8-phase role-split) -> reverted to R6 schedule.

typedef __attribute__((ext_vector_type(8))) short s8vec;    // 8 x bf16 (4 VGPRs)
typedef __attribute__((ext_vector_type(4))) float floatx4;  // MFMA accumulator

__device__ __forceinline__ unsigned short f2bf(float f) {
    union { float f; unsigned u; } v; v.f = f;
    unsigned r = (v.u + 0x7FFFu + ((v.u >> 16) & 1u)) >> 16;
    return (unsigned short)r;
}

__device__ __forceinline__ void gl2lds16(const void* g, void* l) {
    __builtin_amdgcn_global_load_lds(
        (__attribute__((address_space(1))) void*)(g),
        (__attribute__((address_space(3))) void*)(l), 16, 0, 0);
}

// ---- prep: k->padded bf16 + s_w partial dots | W -> Wt2[d][w*512+c] |
//      kp zero-pad rows | s halo zeros ----
__global__ void cvt_kw(const float* __restrict__ k,
                       unsigned short* __restrict__ kp,
                       const float* __restrict__ W, unsigned short* __restrict__ Wt2,
                       const float* __restrict__ b_kernel, float* __restrict__ spart) {
    __shared__ float ldsw[1536];
    int blk = blockIdx.x;
    if (blk < 1024) {                           // k: row-per-wave convert + s_w dots
        int p = blk;                            // 0..1023
        int b = p >> 7;                         // 0..7
        for (int e = threadIdx.x; e < 1536; e += 256) {
            float v = b_kernel[e];
            int c = e / 3, w = e - c * 3;
            ldsw[w * 512 + c] = v;
        }
        __syncthreads();
        int wave = threadIdx.x >> 6, lane = threadIdx.x & 63;
        float bw[3][8];
        #pragma unroll
        for (int w = 0; w < 3; w++)
            #pragma unroll
            for (int i = 0; i < 8; i++) bw[w][i] = ldsw[w * 512 + lane * 8 + i];
        const float* kb = k + (size_t)b * 1024 * 512;
        #pragma unroll
        for (int rr = 0; rr < 2; rr++) {
            int j = (p & 127) * 8 + wave * 2 + rr;
            const float4* kr = (const float4*)(kb + (size_t)j * 512) + lane * 2;
            float4 a0 = kr[0], a1 = kr[1];
            union { unsigned short s[8]; uint4 v; } o;
            o.s[0]=f2bf(a0.x); o.s[1]=f2bf(a0.y); o.s[2]=f2bf(a0.z); o.s[3]=f2bf(a0.w);
            o.s[4]=f2bf(a1.x); o.s[5]=f2bf(a1.y); o.s[6]=f2bf(a1.z); o.s[7]=f2bf(a1.w);
            *(uint4*)(kp + ((size_t)(b * 1028 + j + 1) * 512 + lane * 8)) = o.v;
            float s0 = a0.x*bw[0][0] + a0.y*bw[0][1] + a0.z*bw[0][2] + a0.w*bw[0][3]
                     + a1.x*bw[0][4] + a1.y*bw[0][5] + a1.z*bw[0][6] + a1.w*bw[0][7];
            float s1 = a0.x*bw[1][0] + a0.y*bw[1][1] + a0.z*bw[1][2] + a0.w*bw[1][3]
                     + a1.x*bw[1][4] + a1.y*bw[1][5] + a1.z*bw[1][6] + a1.w*bw[1][7];
            float s2 = a0.x*bw[2][0] + a0.y*bw[2][1] + a0.z*bw[2][2] + a0.w*bw[2][3]
                     + a1.x*bw[2][4] + a1.y*bw[2][5] + a1.z*bw[2][6] + a1.w*bw[2][7];
            #pragma unroll
            for (int off = 32; off > 0; off >>= 1) {
                s0 += __shfl_down(s0, off);
                s1 += __shfl_down(s1, off);
                s2 += __shfl_down(s2, off);
            }
            if (lane == 0) {                    // row j stored at index j+1
                float* sb = spart + b * 1028 + j + 1;
                sb[0]     = s0;
                sb[8224]  = s1;
                sb[16448] = s2;
            }
        }
    } else if (blk < 1536) {                    // Wt2 rows 0..511: one d-row per block
        int d = blk - 1024;
        const float4* wrow = (const float4*)(W + (size_t)d * 1536);
        for (int e = threadIdx.x; e < 384; e += 256) {
            float4 v = wrow[e];
            float va[4] = { v.x, v.y, v.z, v.w };
            #pragma unroll
            for (int i = 0; i < 4; i++) {
                int idx = e * 4 + i;            // idx = c*3 + w
                int c = idx / 3, w = idx - c * 3;
                ldsw[w * 512 + c] = va[i];
            }
        }
        __syncthreads();
        for (int p = threadIdx.x; p < 192; p += 256) {
            union { unsigned short s[8]; uint4 v; } o;
            #pragma unroll
            for (int i = 0; i < 8; i++) o.s[i] = f2bf(ldsw[p * 8 + i]);
            *(uint4*)(Wt2 + (size_t)d * 1536 + p * 8) = o.v;
        }
    } else if (blk < 1544) {                    // kp zero rows 0, 1025..1027
        int z = (blk - 1536) * 256 + threadIdx.x;   // 0..2047
        int b = z >> 8, r = (z >> 6) & 3, ch = z & 63;
        int row = r ? (1024 + r) : 0;
        *(uint4*)(kp + ((size_t)(b * 1028 + row) * 512 + ch * 8)) = make_uint4(0u,0u,0u,0u);
    } else {                                    // s halo zeros (idx 0 and 1025)
        int t = threadIdx.x;
        if (t < 48) {
            int w = t >> 4, rem = t & 15;
            int b = rem >> 1, pos = (rem & 1) ? 1025 : 0;
            spart[w * 8224 + b * 1028 + pos] = 0.0f;
        }
    }
}

// ---- Phase V + q-cvt: blocks 0..511 compute V = kwin @ Wt2^T + Wb
//      (128m x 64n, 4 waves, BK=64 dbuf, XOR-swizzled LDS, XCD = batch);
//      blocks 512..2559 convert q -> bf16 (memory-bound, co-resident:
//      48 KB LDS -> 3 blocks/CU, GEMM grid is 2/CU). ----
__global__ __launch_bounds__(256) void gemm_V_qcvt(const unsigned short* __restrict__ kp,
                                                   const unsigned short* __restrict__ Wt2,
                                                   const float* __restrict__ Wbias,
                                                   unsigned short* __restrict__ V,
                                                   const float* __restrict__ q,
                                                   unsigned short* __restrict__ qbf) {
    __shared__ unsigned short lds_a[2][128 * 64];   // 2 x 16 KB
    __shared__ unsigned short lds_b[2][64 * 64];    // 2 x 8 KB   (48 KB)
    int g = blockIdx.x;
    if (g >= 512) {                     // ---- q conversion path ----
        int t = (g - 512) * 256 + threadIdx.x;      // 0..524287
        const float4* p = (const float4*)q + 2 * (size_t)t;
        float4 a = p[0], b = p[1];
        union { unsigned short s[8]; uint4 v; } o;
        o.s[0]=f2bf(a.x); o.s[1]=f2bf(a.y); o.s[2]=f2bf(a.z); o.s[3]=f2bf(a.w);
        o.s[4]=f2bf(b.x); o.s[5]=f2bf(b.y); o.s[6]=f2bf(b.z); o.s[7]=f2bf(b.w);
        ((uint4*)qbf)[t] = o.v;
        return;
    }
    // ---- GEMM path (R6 form) ----
    int b = g & 7, slot = g >> 3;       // slot 0..63
    int j0 = (slot >> 3) * 128;
    int n0 = (slot & 7) * 64;
    int tid = threadIdx.x, wid = tid >> 6, lane = tid & 63;
    int wm = wid >> 1, wn = wid & 1;
    int crow = lane >> 3;                           // row within 8-row chunk
    int scol = ((lane & 7) ^ crow) * 8;             // inverse-swizzled global col
    const unsigned short* kpb = kp + (size_t)(b * 1028 + j0) * 512;
    floatx4 acc[4][2] = {};

    auto STAGE = [&](int buf, int kk) {
        #pragma unroll
        for (int s = 0; s < 6; ++s) {
            int t = wid * 6 + s;        // 0..23, wave-uniform
            if (t < 16) {               // A: 128 rows x 64k, chunk = 8 rows
                const unsigned short* ga = kpb + (size_t)(t * 8 + crow) * 512 + kk + scol;
                gl2lds16(ga, (char*)lds_a[buf] + t * 1024);
            } else {                    // B: 64 rows x 64k
                int u = t - 16;
                const unsigned short* gb = Wt2 + (size_t)(n0 + u * 8 + crow) * 1536 + kk + scol;
                gl2lds16(gb, (char*)lds_b[buf] + u * 1024);
            }
        }
    };

    STAGE(0, 0);
    __syncthreads();
    int cur = 0;
    int ra = lane & 15, hi = lane >> 4;
    for (int kt = 0; kt < 24; ++kt) {
        if (kt < 23) STAGE(cur ^ 1, (kt + 1) * 64);
        #pragma unroll
        for (int ks = 0; ks < 2; ++ks) {
            s8vec af[4], bfr[2];
            #pragma unroll
            for (int mi = 0; mi < 4; mi++) {
                int R = wm * 64 + mi * 16 + ra;
                af[mi] = *(const s8vec*)((const char*)lds_a[cur] + R * 128 + (((ks << 2) + hi) ^ (R & 7)) * 16);
            }
            #pragma unroll
            for (int ni = 0; ni < 2; ni++) {
                int R = wn * 32 + ni * 16 + ra;
                bfr[ni] = *(const s8vec*)((const char*)lds_b[cur] + R * 128 + (((ks << 2) + hi) ^ (R & 7)) * 16);
            }
            #pragma unroll
            for (int mi = 0; mi < 4; mi++)
                #pragma unroll
                for (int ni = 0; ni < 2; ni++)
                    acc[mi][ni] = __builtin_amdgcn_mfma_f32_16x16x32_bf16(af[mi], bfr[ni], acc[mi][ni], 0, 0, 0);
        }
        if (kt < 23) { __syncthreads(); cur ^= 1; }
    }

    int cl = lane & 15, qd = lane >> 4;
    #pragma unroll
    for (int mi = 0; mi < 4; mi++) {
        #pragma unroll
        for (int ni = 0; ni < 2; ni++) {
            int col = n0 + wn * 32 + ni * 16 + cl;
            float wb = Wbias[col];
            #pragma unroll
            for (int r = 0; r < 4; r++) {
                int m_g = b * 1024 + j0 + wm * 64 + mi * 16 + qd * 4 + r;
                V[(size_t)m_g * 512 + col] = f2bf(acc[mi][ni][r] + wb);
            }
        }
    }
}

// ---- Phase B': out[b,i,j] = sum_d qbf[b,i,d]*V[b,j,d] + t[b,j] + b_bias + bias_b
//      t[b,j] = s0[j-1] + s1[j] + s2[j+1] via halo-padded spart.
//      128x128 tiles, 4 waves, BK=64 dbuf, grid 512, XCD = batch. ----
__global__ __launch_bounds__(256) void gemm_QV(const unsigned short* __restrict__ qbf,
                                               const unsigned short* __restrict__ V,
                                               const float* __restrict__ spart,
                                               const float* __restrict__ b_bias,
                                               const float* __restrict__ bias_b,
                                               float* __restrict__ out) {
    __shared__ unsigned short lds_a[2][128 * 64];   // 2 x 16 KB
    __shared__ unsigned short lds_b[2][128 * 64];   // 2 x 16 KB
    int g = blockIdx.x;                 // 0..511
    int b = g & 7, slot = g >> 3;       // slot 0..63
    int i0 = (slot >> 3) * 128;
    int j0 = (slot & 7) * 128;
    int tid = threadIdx.x, wid = tid >> 6, lane = tid & 63;
    int wm = wid >> 1, wn = wid & 1;
    int crow = lane >> 3;
    int scol = ((lane & 7) ^ crow) * 8;
    const unsigned short* Ab = qbf + (size_t)b * 1024 * 512;
    const unsigned short* Bb = V + (size_t)b * 1024 * 512;
    floatx4 acc[4][4] = {};

    auto STAGE = [&](int buf, int kk) {
        #pragma unroll
        for (int s = 0; s < 8; ++s) {
            int t = wid * 8 + s;        // 0..31, wave-uniform
            if (t < 16) {
                const unsigned short* ga = Ab + (size_t)(i0 + t * 8 + crow) * 512 + kk + scol;
                gl2lds16(ga, (char*)lds_a[buf] + t * 1024);
            } else {
                int u = t - 16;
                const unsigned short* gb = Bb + (size_t)(j0 + u * 8 + crow) * 512 + kk + scol;
                gl2lds16(gb, (char*)lds_b[buf] + u * 1024);
            }
        }
    };

    STAGE(0, 0);
    __syncthreads();
    int cur = 0;
    int ra = lane & 15, hi = lane >> 4;
    for (int kt = 0; kt < 8; ++kt) {
        if (kt < 7) STAGE(cur ^ 1, (kt + 1) * 64);
        #pragma unroll
        for (int ks = 0; ks < 2; ++ks) {
            s8vec af[4], bfr[4];
            #pragma unroll
            for (int mi = 0; mi < 4; mi++) {
                int R = wm * 64 + mi * 16 + ra;
                af[mi] = *(const s8vec*)((const char*)lds_a[cur] + R * 128 + (((ks << 2) + hi) ^ (R & 7)) * 16);
            }
            #pragma unroll
            for (int ni = 0; ni < 4; ni++) {
                int R = wn * 64 + ni * 16 + ra;
                bfr[ni] = *(const s8vec*)((const char*)lds_b[cur] + R * 128 + (((ks << 2) + hi) ^ (R & 7)) * 16);
            }
            #pragma unroll
            for (int mi = 0; mi < 4; mi++)
                #pragma unroll
                for (int ni = 0; ni < 4; ni++)
                    acc[mi][ni] = __builtin_amdgcn_mfma_f32_16x16x32_bf16(af[mi], bfr[ni], acc[mi][ni], 0, 0, 0);
        }
        if (kt < 7) { __syncthreads(); cur ^= 1; }
    }

    int cl = lane & 15, qd = lane >> 4;
    float bbsum = b_bias[0] + bias_b[0];
    const float* sb = spart + b * 1028;     // [w] stride 8224, row j at idx j+1
    float tv[4];
    #pragma unroll
    for (int ni = 0; ni < 4; ni++) {
        int jg = j0 + wn * 64 + ni * 16 + cl;
        tv[ni] = sb[jg] + sb[8224 + jg + 1] + sb[16448 + jg + 2] + bbsum;
    }
    #pragma unroll
    for (int mi = 0; mi < 4; mi++) {
        #pragma unroll
        for (int r = 0; r < 4; r++) {
            int i_g = i0 + wm * 64 + mi * 16 + qd * 4 + r;
            float* orow = out + ((size_t)(b * 1024 + i_g)) * 1024 + j0;
            #pragma unroll
            for (int ni = 0; ni < 4; ni++) {
                int j_loc = wn * 64 + ni * 16 + cl;
                orow[j_loc] = acc[mi][ni][r] + tv[ni];
            }
        }
    }
}

extern "C" void kernel_launch(void* const* d_in, const int* in_sizes, int n_in,
                              void* d_out, int out_size, void* d_ws, size_t ws_size,
                              hipStream_t stream) {
    const float* q        = (const float*)d_in[0];  // (8,1024,512)
    const float* k        = (const float*)d_in[1];  // (8,1024,512)
    const float* W_kernel = (const float*)d_in[2];  // (512,1536)
    const float* b_kernel = (const float*)d_in[3];  // (1536,)
    const float* W_bias   = (const float*)d_in[4];  // (512,1)
    const float* b_bias   = (const float*)d_in[5];  // (1,)
    const float* bias_b   = (const float*)d_in[6];  // (1,)
    float* out = (float*)d_out;                     // (8,1024,1024)

    // workspace carve (bytes):
    //   q_bf 8M | kp 8.03M + 16K headroom | Wt2 1.5M | V 8M | spart 3*8224*4
    char* ws = (char*)d_ws;
    unsigned short* q_bf = (unsigned short*)(ws);
    unsigned short* kp   = (unsigned short*)(ws + 8388608);
    unsigned short* Wt2  = (unsigned short*)(ws + 8388608 + 8421376 + 16384);
    unsigned short* V    = (unsigned short*)(ws + 8388608 + 8421376 + 16384 + 1572864);
    float*          sp   = (float*)(ws + 8388608 + 8421376 + 16384 + 1572864 + 8388608);

    cvt_kw<<<1545, 256, 0, stream>>>(k, kp, W_kernel, Wt2, b_kernel, sp);
    gemm_V_qcvt<<<2560, 256, 0, stream>>>(kp, Wt2, W_bias, V, q, q_bf);
    gemm_QV<<<512, 256, 0, stream>>>(q_bf, V, sp, b_bias, bias_b, out);
}